// Round 2
// baseline (453.384 us; speedup 1.0000x reference)
//
#include <hip/hip_runtime.h>
#include <hip/hip_bf16.h>

typedef short short8 __attribute__((ext_vector_type(8)));
typedef float f32x16 __attribute__((ext_vector_type(16)));
typedef float f32x4 __attribute__((ext_vector_type(4)));

#define BM 128
#define BN 128

typedef const __attribute__((address_space(1))) void gas_t;
typedef __attribute__((address_space(3))) void las_t;

__device__ __forceinline__ unsigned short f2bf(float f) {
  unsigned int u = __float_as_uint(f);
  u += 0x7FFFu + ((u >> 16) & 1u);   // round-to-nearest-even
  return (unsigned short)(u >> 16);
}

// tanh via single v_exp_f32 + v_rcp_f32: tanh(x) = 1 - 2/(e^2x + 1).
__device__ __forceinline__ float fast_tanh(float x) {
  x = fminf(fmaxf(x, -10.f), 10.f);
  float t = __builtin_amdgcn_exp2f(x * 2.8853900817779268f);  // 2*log2(e)
  return 1.f - 2.f * __builtin_amdgcn_rcpf(t + 1.f);
}

struct GemmP {
  const unsigned short* A;
  const unsigned short* Bm;
  void* C;
  const float* A2f;            // f32 second A source for k >= kSplit (converted during staging)
  // alt pointer set for merged launches: used when z >= zSplit
  const unsigned short* A_b;
  const unsigned short* Bm_b;
  void* C_b;
  const float* A2f_b;
  const float* mask_p;
  const float* mask_s;
  const float* bias;
  const float* bias_b;
  long long sAb, sAh, sBb, sBh, sCb, sCh;
  int lda, lda2, ldb, ldc, M, N, K, Hh, kSplit, zSplit, nbx, nby;
};

// ---------------------------------------------------------------------------
// Legacy 128x128 / 256-thread kernel (kept for steps 4 and 5).
// TA: 0 = A is M x K row-major (lds-DMA staging, pitch 32); 1 = A stored K x M.
// EPI: 0 bf16 store; 1 tanh*mask bf16; 2 relu+atomicMax f32 pool; 3 +bias,relu f32.
template <int TA, int EPI>
__device__ __forceinline__ void gemm_body(const GemmP& p, int bx, int by, int bz, char* smem_) {
  constexpr int PA = (TA == 0) ? 32 : 40;
  constexpr int HSA = (TA == 0) ? 4096 : 5120;  // shorts per A half-tile
  unsigned short* As = (unsigned short*)smem_;
  unsigned short* Bs = (unsigned short*)(smem_ + 2 * HSA * 2);

  int z = bz;
  const unsigned short* Abase = p.A;
  const unsigned short* Bbase = p.Bm;
  void* Cvp = p.C;
  const float* A2f = p.A2f;
  const float* bias = p.bias;
  if (p.zSplit && z >= p.zSplit) {
    z -= p.zSplit;
    Abase = p.A_b; Bbase = p.Bm_b; Cvp = p.C_b; A2f = p.A2f_b; bias = p.bias_b;
  }
  const int zb = z / p.Hh, zh = z % p.Hh;
  const unsigned short* A = Abase + (size_t)zb * p.sAb + (size_t)zh * p.sAh;
  const unsigned short* B = Bbase + (size_t)zb * p.sBb + (size_t)zh * p.sBh;
  const int m0 = bx * BM, n0 = by * BN;
  const int tid = threadIdx.x;
  const int wid = tid >> 6, lane = tid & 63;
  const int wm = (wid >> 1) * 64, wn = (wid & 1) * 64;
  const int lrow = lane & 31;          // row within 32x32 frag
  const int lk8 = (lane >> 5) * 8;     // k-offset within 16-k chunk

  f32x16 acc[2][2] = {};

  const int dm = tid >> 2, dkg = tid & 3;

  auto mfma_block = [&]() {
#pragma unroll
    for (int h = 0; h < 2; ++h)
#pragma unroll
      for (int kc = 0; kc < 2; ++kc) {
        short8 af[2], bfv[2];
#pragma unroll
        for (int mt = 0; mt < 2; ++mt)
          af[mt] = *(const short8*)&As[h * HSA + (wm + mt * 32 + lrow) * PA + kc * 16 + lk8];
#pragma unroll
        for (int nt = 0; nt < 2; ++nt)
          bfv[nt] = *(const short8*)&Bs[h * 4096 + (wn + nt * 32 + lrow) * 32 + kc * 16 + lk8];
#pragma unroll
        for (int mt = 0; mt < 2; ++mt)
#pragma unroll
          for (int nt = 0; nt < 2; ++nt)
            acc[mt][nt] = __builtin_amdgcn_mfma_f32_32x32x16_bf16(af[mt], bfv[nt], acc[mt][nt], 0, 0, 0);
      }
  };
  auto stage_b = [&](int k0) {
#pragma unroll
    for (int h = 0; h < 2; ++h)
#pragma unroll
      for (int q = 0; q < 2; ++q) {
        const unsigned short* src = B + (size_t)(n0 + q * 64 + dm) * p.ldb + (k0 + h * 32 + dkg * 8);
        __builtin_amdgcn_global_load_lds((gas_t*)src,
                                         (las_t*)&Bs[h * 4096 + q * 2048 + wid * 512],
                                         16, 0, 0);
      }
  };

  const int nIter = p.K >> 6;
  const int nIter1 = p.kSplit ? (p.kSplit >> 6) : nIter;

  for (int it = 0; it < nIter1; ++it) {
    const int k0 = it << 6;
    if (TA == 0) {
#pragma unroll
      for (int h = 0; h < 2; ++h)
#pragma unroll
        for (int q = 0; q < 2; ++q) {
          const unsigned short* src = A + (size_t)(m0 + q * 64 + dm) * p.lda + (k0 + h * 32 + dkg * 8);
          __builtin_amdgcn_global_load_lds((gas_t*)src,
                                           (las_t*)&As[h * HSA + q * 2048 + wid * 512],
                                           16, 0, 0);
        }
    } else {
      const int kk = tid & 31, mg = (tid >> 5) << 4;
#pragma unroll
      for (int h = 0; h < 2; ++h) {
        const unsigned short* src = A + (size_t)(k0 + h * 32 + kk) * p.lda + (m0 + mg);
        uint4 v0 = *(const uint4*)src;
        uint4 v1 = *(const uint4*)(src + 8);
        unsigned short tmp[16];
        *(uint4*)&tmp[0] = v0;
        *(uint4*)&tmp[8] = v1;
#pragma unroll
        for (int j = 0; j < 16; ++j) As[h * HSA + (mg + j) * PA + kk] = tmp[j];
      }
    }
    stage_b(k0);
    __syncthreads();
    mfma_block();
    __syncthreads();
  }

  // phase 2 (TA=0 only in practice): A from f32 source with in-register convert
  if (TA == 0 && p.kSplit) {
    for (int it = nIter1; it < nIter; ++it) {
      const int k0 = it << 6;
#pragma unroll
      for (int h = 0; h < 2; ++h) {
        const int ko = k0 + h * 32 - p.kSplit;
#pragma unroll
        for (int q = 0; q < 2; ++q) {
          const float* src = A2f + (size_t)(m0 + q * 64 + dm) * p.lda2 + (ko + dkg * 8);
          float4 v0 = *(const float4*)src;
          float4 v1 = *(const float4*)(src + 4);
          __attribute__((aligned(16))) unsigned short t[8];
          t[0] = f2bf(v0.x); t[1] = f2bf(v0.y); t[2] = f2bf(v0.z); t[3] = f2bf(v0.w);
          t[4] = f2bf(v1.x); t[5] = f2bf(v1.y); t[6] = f2bf(v1.z); t[7] = f2bf(v1.w);
          *(uint4*)&As[h * HSA + (q * 64 + dm) * 32 + dkg * 8] = *(const uint4*)t;
        }
      }
      stage_b(k0);
      __syncthreads();
      mfma_block();
      __syncthreads();
    }
  }

  unsigned short* Cu = (unsigned short*)Cvp + (size_t)zb * p.sCb + (size_t)zh * p.sCh;
  float* Cf = (float*)Cvp + (size_t)zb * p.sCb + (size_t)zh * p.sCh;

  const int rbase = 4 * (lane >> 5);

  float mp[2][16], ms[2];
  if constexpr (EPI == 1) {
#pragma unroll
    for (int mt = 0; mt < 2; ++mt)
#pragma unroll
      for (int reg = 0; reg < 16; ++reg) {
        const int rl = (reg & 3) + 8 * (reg >> 2) + rbase;
        mp[mt][reg] = p.mask_p[(size_t)zb * p.M + (m0 + wm + mt * 32 + rl)];
      }
#pragma unroll
    for (int nt = 0; nt < 2; ++nt)
      ms[nt] = p.mask_s[(size_t)zb * p.N + (n0 + wn + nt * 32 + lrow)];
  }
  if constexpr (EPI == 3) {
#pragma unroll
    for (int nt = 0; nt < 2; ++nt)
      ms[nt] = bias[n0 + wn + nt * 32 + lrow];
  }

#pragma unroll
  for (int mt = 0; mt < 2; ++mt) {
#pragma unroll
    for (int nt = 0; nt < 2; ++nt) {
      f32x16 a = acc[mt][nt];
#pragma unroll
      for (int reg = 0; reg < 16; ++reg) {
        const int rl = (reg & 3) + 8 * (reg >> 2) + rbase;
        const int grow = m0 + wm + mt * 32 + rl;
        const int gcol = n0 + wn + nt * 32 + lrow;
        const size_t idx = (size_t)grow * p.ldc + gcol;
        const float v = a[reg];
        if constexpr (EPI == 0) {
          Cu[idx] = f2bf(v);
        } else if constexpr (EPI == 1) {
          Cu[idx] = f2bf(fast_tanh(v) * (mp[mt][reg] * ms[nt]));
        } else if constexpr (EPI == 2) {
          atomicMax((int*)Cf + idx, __float_as_int(fmaxf(v, 0.f)));
        } else {
          Cf[idx] = fmaxf(v + ms[nt], 0.f);
        }
      }
    }
  }
}

template <int TA, int EPI>
__global__ __launch_bounds__(256) void gemm_k(GemmP p) {
  extern __shared__ char smem[];
  gemm_body<TA, EPI>(p, blockIdx.x, blockIdx.y, blockIdx.z, smem);
}

template <int TA1, int EPI1, int TA2, int EPI2>
__global__ __launch_bounds__(256) void gemm_pair_k(GemmP a, GemmP b, int nA) {
  extern __shared__ char smem[];
  int bid = blockIdx.x;
  if (bid < nA) {
    const int per = a.nbx * a.nby;
    const int z = bid / per, r = bid % per;
    gemm_body<TA1, EPI1>(a, r % a.nbx, r / a.nbx, z, smem);
  } else {
    bid -= nA;
    const int per = b.nbx * b.nby;
    const int z = bid / per, r = bid % per;
    gemm_body<TA2, EPI2>(b, r % b.nbx, r / b.nbx, z, smem);
  }
}

// ---------------------------------------------------------------------------
// gemm9: 256x256 reg-staged deep pipeline (steps 2 and 3).
// 512 threads = 8 waves as 2(M) x 4(N); wave tile 128x64 = 8x4 frags of 16x16x32.
// BK=64. LDS: 2 slots x 64 KiB (A 256x64 + B 256x64 bf16) = 128 KiB.
// Staging = global_load_dwordx4 -> VGPR -> swizzled ds_write_b128 (NOT lds-DMA:
// measured ~80 cyc/instr global_load_lds service rate capped both prior kernels
// at ~626 TF; the vector-load path has deep MLP).
// Per K-tile, 4 phases (ks x m-half), each 16 MFMA; loads issued in phases A/B
// (T14 issue-early), counted vmcnt(4)/vmcnt(0) + ds_write in phases C/D,
// ONE __syncthreads per K-tile (reads hit slot, writes hit other slot).
// LDS swizzle: byte_col ^= (row&7)<<4 on both write and read (bank-conflict-free).
// EPI: 0 = bf16 store; 1 = tanh*mask bf16.
#define VMW4() asm volatile("s_waitcnt vmcnt(4)" ::: "memory")
#define VMW0() asm volatile("s_waitcnt vmcnt(0)" ::: "memory")
#define CBAR() asm volatile("" ::: "memory")

template <int EPI>
__device__ __forceinline__ void gemm9_body(const GemmP& p, int bx, int by, int bz, char* smem_) {
  int z = bz;
  const unsigned short* Abase = p.A;
  const unsigned short* Bbase = p.Bm;
  void* Cvp = p.C;
  if (p.zSplit && z >= p.zSplit) {
    z -= p.zSplit;
    Abase = p.A_b; Bbase = p.Bm_b; Cvp = p.C_b;
  }
  const int zb = z / p.Hh, zh = z % p.Hh;
  const unsigned short* A = Abase + (size_t)zb * p.sAb + (size_t)zh * p.sAh;
  const unsigned short* B = Bbase + (size_t)zb * p.sBb + (size_t)zh * p.sBh;
  const int m0 = bx * 256, n0 = by * 256;
  const int tid = threadIdx.x;
  const int wid = tid >> 6, lane = tid & 63;
  const int wm = wid >> 2, wn = wid & 3;        // 2 x 4 wave grid
  const int lrow = lane & 15, lhi = lane >> 4;  // MFMA 16x16x32 lane decomposition

  unsigned short* lds = (unsigned short*)smem_;

  // staging: thread covers half a row (64 B) of the 256x64 A-tile and B-tile
  const int srow = tid >> 1;            // 0..255
  const int scS = (tid & 1) * 32;       // col base in shorts (0 or 32)
  const int swW = (srow & 7) << 3;      // write-side swizzle, short units

  // read-side swizzled lane offsets (bytes within slot)
  const int swr = (lrow & 7) << 4;                 // byte swizzle (row&7 == lrow&7)
  const int colA = (lhi * 16) ^ swr;               // ks=0 byte col
  const int rowA0 = (wm * 128 + lrow) * 128 + colA;            // A region byte off
  const int rowB0 = 32768 + (wn * 64 + lrow) * 128 + colA;     // B region byte off

  f32x4 acc[8][4] = {};
  uint4 stA[4], stB[4];

  auto loadA = [&](int k0) {
    const unsigned short* s = A + (size_t)(m0 + srow) * p.lda + k0 + scS;
#pragma unroll
    for (int j = 0; j < 4; ++j) stA[j] = *(const uint4*)(s + j * 8);
    CBAR();
  };
  auto loadB = [&](int k0) {
    const unsigned short* s = B + (size_t)(n0 + srow) * p.ldb + k0 + scS;
#pragma unroll
    for (int j = 0; j < 4; ++j) stB[j] = *(const uint4*)(s + j * 8);
    CBAR();
  };
  auto writeA = [&](int other) {
#pragma unroll
    for (int j = 0; j < 4; ++j)
      *(uint4*)&lds[other * 32768 + srow * 64 + ((scS + j * 8) ^ swW)] = stA[j];
  };
  auto writeB = [&](int other) {
#pragma unroll
    for (int j = 0; j < 4; ++j)
      *(uint4*)&lds[other * 32768 + 16384 + srow * 64 + ((scS + j * 8) ^ swW)] = stB[j];
  };

  const int nt = p.K >> 6;   // K-tiles of 64

  // prologue: tile 0 -> slot 0
  loadA(0); loadB(0);
  VMW4(); writeA(0);
  VMW0(); writeB(0);
  __syncthreads();

  for (int t = 0; t < nt; ++t) {
    const int slot = t & 1, other = slot ^ 1;
    const char* sb = smem_ + slot * 65536;
    const int kn = (t + 1) << 6;
    short8 af[4], bv[4];

    // ---- phase A (ks0, m-half 0): issue A-loads(t+1), read B-ks0 + A0..3-ks0
    if (t + 1 < nt) loadA(kn);
#pragma unroll
    for (int fn = 0; fn < 4; ++fn) bv[fn] = *(const short8*)(sb + rowB0 + fn * 2048);
#pragma unroll
    for (int fm = 0; fm < 4; ++fm) af[fm] = *(const short8*)(sb + rowA0 + fm * 2048);
    __builtin_amdgcn_s_setprio(1);
#pragma unroll
    for (int fm = 0; fm < 4; ++fm)
#pragma unroll
      for (int fn = 0; fn < 4; ++fn)
        acc[fm][fn] = __builtin_amdgcn_mfma_f32_16x16x32_bf16(af[fm], bv[fn], acc[fm][fn], 0, 0, 0);
    __builtin_amdgcn_s_setprio(0);

    // ---- phase B (ks0, m-half 1): issue B-loads(t+1), read A4..7-ks0 (B held)
    if (t + 1 < nt) loadB(kn);
#pragma unroll
    for (int fm = 0; fm < 4; ++fm) af[fm] = *(const short8*)(sb + rowA0 + (4 + fm) * 2048);
    __builtin_amdgcn_s_setprio(1);
#pragma unroll
    for (int fm = 0; fm < 4; ++fm)
#pragma unroll
      for (int fn = 0; fn < 4; ++fn)
        acc[4 + fm][fn] = __builtin_amdgcn_mfma_f32_16x16x32_bf16(af[fm], bv[fn], acc[4 + fm][fn], 0, 0, 0);
    __builtin_amdgcn_s_setprio(0);

    // ---- phase C (ks1, m-half 0): A(t+1) arrived -> ds_write to other slot
    if (t + 1 < nt) { VMW4(); writeA(other); }
#pragma unroll
    for (int fn = 0; fn < 4; ++fn) bv[fn] = *(const short8*)(sb + (rowB0 ^ 64) + fn * 2048);
#pragma unroll
    for (int fm = 0; fm < 4; ++fm) af[fm] = *(const short8*)(sb + (rowA0 ^ 64) + fm * 2048);
    __builtin_amdgcn_s_setprio(1);
#pragma unroll
    for (int fm = 0; fm < 4; ++fm)
#pragma unroll
      for (int fn = 0; fn < 4; ++fn)
        acc[fm][fn] = __builtin_amdgcn_mfma_f32_16x16x32_bf16(af[fm], bv[fn], acc[fm][fn], 0, 0, 0);
    __builtin_amdgcn_s_setprio(0);

    // ---- phase D (ks1, m-half 1): B(t+1) arrived -> ds_write to other slot
    if (t + 1 < nt) { VMW0(); writeB(other); }
#pragma unroll
    for (int fm = 0; fm < 4; ++fm) af[fm] = *(const short8*)(sb + (rowA0 ^ 64) + (4 + fm) * 2048);
    __builtin_amdgcn_s_setprio(1);
#pragma unroll
    for (int fm = 0; fm < 4; ++fm)
#pragma unroll
      for (int fn = 0; fn < 4; ++fn)
        acc[4 + fm][fn] = __builtin_amdgcn_mfma_f32_16x16x32_bf16(af[fm], bv[fn], acc[4 + fm][fn], 0, 0, 0);
    __builtin_amdgcn_s_setprio(0);

    if (t + 1 < nt) __syncthreads();
  }

  // ---- epilogue ----
  unsigned short* Cu = (unsigned short*)Cvp + (size_t)zb * p.sCb + (size_t)zh * p.sCh;

  float ms[4];
  if constexpr (EPI == 1) {
#pragma unroll
    for (int fn = 0; fn < 4; ++fn)
      ms[fn] = p.mask_s[(size_t)zb * p.N + (n0 + wn * 64 + fn * 16 + lrow)];
  }

#pragma unroll
  for (int fm = 0; fm < 8; ++fm)
#pragma unroll
    for (int fn = 0; fn < 4; ++fn) {
      f32x4 a = acc[fm][fn];
      const int gcol = n0 + wn * 64 + fn * 16 + lrow;
#pragma unroll
      for (int reg = 0; reg < 4; ++reg) {
        const int grow = m0 + wm * 128 + fm * 16 + lhi * 4 + reg;
        const size_t idx = (size_t)grow * p.ldc + gcol;
        if constexpr (EPI == 0) {
          Cu[idx] = f2bf(a[reg]);
        } else {
          const float mp = p.mask_p[(size_t)zb * p.M + grow];
          Cu[idx] = f2bf(fast_tanh(a[reg]) * (mp * ms[fn]));
        }
      }
    }
}

template <int EPI>
__global__ __launch_bounds__(512, 2) void gemm9_k(GemmP p) {
  extern __shared__ char smem[];
  gemm9_body<EPI>(p, blockIdx.x, blockIdx.y, blockIdx.z, smem);
}

template <int E1, int E2>
__global__ __launch_bounds__(512, 2) void gemm9_pair_k(GemmP a, GemmP b, int nA) {
  extern __shared__ char smem[];
  int bid = blockIdx.x;
  if (bid < nA) {
    const int per = a.nbx * a.nby;
    const int z = bid / per, r = bid % per;
    gemm9_body<E1>(a, r % a.nbx, r / a.nbx, z, smem);
  } else {
    bid -= nA;
    const int per = b.nbx * b.nby;
    const int z = bid / per, r = bid % per;
    gemm9_body<E2>(b, r % b.nbx, r / b.nbx, z, smem);
  }
}

// ---- fused preamble: input cvt, 4 weight transposes, pool zeroing ----
__device__ __forceinline__ void trans_body(const float* src, unsigned short* dst,
                                           int R, int C, int bx, int by, float (*tile)[33]) {
  const int r0 = by * 32, c0 = bx * 32;
  const int tx = threadIdx.x & 31, ty = threadIdx.x >> 5;  // 32 x 8
#pragma unroll
  for (int j = 0; j < 4; ++j)
    tile[ty + j * 8][tx] = src[(size_t)(r0 + ty + j * 8) * C + (c0 + tx)];
  __syncthreads();
#pragma unroll
  for (int j = 0; j < 4; ++j)
    dst[(size_t)(c0 + ty + j * 8) * R + (r0 + tx)] = f2bf(tile[tx][ty + j * 8]);
}

__global__ __launch_bounds__(256) void prep_k(const float* P, const float* S,
                                              unsigned short* Pbf, unsigned short* Sbf,
                                              const float* W_aff, unsigned short* WaT,
                                              const float* W_p, unsigned short* WpT,
                                              const float* W_s, unsigned short* WsT,
                                              const float* W_fp, unsigned short* WfpT,
                                              const float* W_fs, unsigned short* WfsT,
                                              float* poolz) {
  __shared__ float tile[32][33];
  const int bid = blockIdx.x;
  if (bid < 8192) {
    const int n4 = 1048576;  // 16*512*512/4
    int i = bid * 256 + threadIdx.x;
    const float4* s = (const float4*)P;
    ushort4* d = (ushort4*)Pbf;
    if (i >= n4) { i -= n4; s = (const float4*)S; d = (ushort4*)Sbf; }
    float4 v = s[i];
    ushort4 o;
    o.x = f2bf(v.x); o.y = f2bf(v.y); o.z = f2bf(v.z); o.w = f2bf(v.w);
    d[i] = o;
  } else if (bid < 10240) {
    const int l = bid - 8192;                      // 16x16 tiles x 8 heads
    const int z = l >> 8, r = l & 255;
    trans_body(W_aff + (size_t)z * 262144, WaT + (size_t)z * 262144, 512, 512,
               r & 15, r >> 4, tile);
  } else if (bid < 11264) {
    const int l = bid - 10240;                     // 32x16 tiles x 2
    const int z = l >> 9, r = l & 511;
    trans_body(z ? W_s : W_p, z ? WsT : WpT, 512, 1024, r & 31, r >> 5, tile);
  } else if (bid < 11904) {
    const int l = bid - 11264;                     // 16x20 tiles x 2
    const int z = l / 320, r = l % 320;
    trans_body(z ? W_fs : W_fp, z ? WfsT : WfpT, 640, 512, r & 15, r >> 4, tile);
  } else {
    const int i = (bid - 11904) * 256 + threadIdx.x;  // 524288 float4s = 8.4 MB
    ((float4*)poolz)[i] = float4{0.f, 0.f, 0.f, 0.f};
  }
}

extern "C" void kernel_launch(void* const* d_in, const int* in_sizes, int n_in,
                              void* d_out, int out_size, void* d_ws, size_t ws_size,
                              hipStream_t stream) {
  (void)in_sizes; (void)n_in; (void)out_size; (void)ws_size;
  const float* primary   = (const float*)d_in[0];
  const float* secondary = (const float*)d_in[1];
  const float* pmask     = (const float*)d_in[2];
  const float* smask     = (const float*)d_in[3];
  const float* W_aff     = (const float*)d_in[4];
  const float* W_p       = (const float*)d_in[5];
  const float* W_s       = (const float*)d_in[6];
  const float* W_fp      = (const float*)d_in[7];
  const float* b_fp      = (const float*)d_in[8];
  const float* W_fs      = (const float*)d_in[9];
  const float* b_fs      = (const float*)d_in[10];

  constexpr int Bb = 16, L = 512, Dd = 512, Hh = 8, HDd = 128, INNER = 1024, CAT = 640;
  constexpr int NT = Hh * Dd;                      // 4096
  constexpr long long LD = (long long)L * Dd;      // 262144
  constexpr long long LL = (long long)L * L;       // 262144

  // one-time: allow 128 KiB dynamic LDS on the gemm9 kernels
  static bool s_attr = [] {
    hipFuncSetAttribute(reinterpret_cast<const void*>(&gemm9_pair_k<0, 0>),
                        hipFuncAttributeMaxDynamicSharedMemorySize, 131072);
    hipFuncSetAttribute(reinterpret_cast<const void*>(&gemm9_k<1>),
                        hipFuncAttributeMaxDynamicSharedMemorySize, 131072);
    return true;
  }();
  (void)s_attr;

  char* base = (char*)d_ws;
  size_t off = 0;
  auto alloc = [&](size_t bytes) -> void* {
    void* r = base + off;
    off += (bytes + 255) & ~(size_t)255;
    return r;
  };

  unsigned short* Pbf   = (unsigned short*)alloc((size_t)Bb * L * Dd * 2);
  unsigned short* Sbf   = (unsigned short*)alloc((size_t)Bb * L * Dd * 2);
  unsigned short* WaT   = (unsigned short*)alloc((size_t)NT * Dd * 2);        // [h*512+f][e]
  unsigned short* WpT   = (unsigned short*)alloc((size_t)INNER * Dd * 2);     // [n][e]
  unsigned short* WsT   = (unsigned short*)alloc((size_t)INNER * Dd * 2);
  unsigned short* WfpT  = (unsigned short*)alloc((size_t)Dd * CAT * 2);       // [n][k]
  unsigned short* WfsT  = (unsigned short*)alloc((size_t)Dd * CAT * 2);
  unsigned short* psT   = (unsigned short*)alloc((size_t)Bb * INNER * L * 2); // [b][d][j]
  unsigned short* ppT   = (unsigned short*)alloc((size_t)Bb * INNER * L * 2); // [b][d][i]
  unsigned short* Tbuf  = (unsigned short*)alloc((size_t)Bb * L * NT * 2);    // [b*L+i][h*512+f]
  unsigned short* affb  = (unsigned short*)alloc((size_t)Bb * Hh * L * L * 2);
  float* pool_p = (float*)alloc((size_t)Bb * L * HDd * 4);                    // adjacent with pool_s
  float* pool_s = (float*)alloc((size_t)Bb * L * HDd * 4);

  // ---- 1) fused preamble ----
  prep_k<<<dim3(13952), dim3(256), 0, stream>>>(primary, secondary, Pbf, Sbf,
                                                W_aff, WaT, W_p, WpT, W_s, WsT,
                                                W_fp, WfpT, W_fs, WfsT, pool_p);

  // ---- 2) Tbuf = P @ Waff(stacked)  ||  psT/ppT = (S@W_s)^T / (P@W_p)^T ----
  // gemm9: 256x256 reg-staged pipeline, 512 threads, 2-slot LDS dbuf
  {
    GemmP a{};
    a.A = Pbf; a.lda = Dd;
    a.Bm = WaT; a.ldb = Dd;
    a.C = Tbuf; a.ldc = NT;
    a.M = Bb * L; a.N = NT; a.K = Dd; a.Hh = 1; a.nbx = 32; a.nby = 16;

    GemmP b{};
    b.A = WsT; b.lda = Dd; b.sAb = 0;
    b.Bm = Sbf; b.ldb = Dd; b.sBb = LD;
    b.C = psT; b.ldc = L; b.sCb = (long long)INNER * L;
    b.A_b = WpT; b.Bm_b = Pbf; b.C_b = ppT;
    b.M = INNER; b.N = L; b.K = Dd; b.Hh = 1; b.zSplit = Bb; b.nbx = 4; b.nby = 2;

    gemm9_pair_k<0, 0><<<dim3(512 + 256), dim3(512), 131072, stream>>>(a, b, 512);
  }

  // ---- 3) aff[b,h] = tanh(T[b,h] @ S_b^T) * mask ----
  {
    GemmP g{};
    g.A = Tbuf; g.lda = NT; g.sAb = (long long)L * NT; g.sAh = Dd;
    g.Bm = Sbf; g.ldb = Dd; g.sBb = LD; g.sBh = 0;
    g.C = affb; g.ldc = L; g.sCb = (long long)Hh * LL; g.sCh = LL;
    g.mask_p = pmask; g.mask_s = smask;
    g.M = L; g.N = L; g.K = Dd; g.Hh = Hh;
    gemm9_k<1><<<dim3(2, 2, Bb * Hh), dim3(512), 131072, stream>>>(g);
  }

  // ---- 4) pool_s (fast A)  ||  pool_p (A = affb as K x M) ----
  {
    GemmP g4{};
    g4.A = affb; g4.lda = L; g4.sAb = (long long)Hh * LL; g4.sAh = LL;
    g4.Bm = psT; g4.ldb = L; g4.sBb = (long long)INNER * L; g4.sBh = (long long)HDd * L;
    g4.C = pool_s; g4.ldc = HDd; g4.sCb = (long long)L * HDd; g4.sCh = 0;
    g4.M = L; g4.N = HDd; g4.K = L; g4.Hh = Hh; g4.nbx = 4; g4.nby = 1;

    GemmP g5 = g4;
    g5.Bm = ppT;
    g5.C = pool_p;

    gemm_pair_k<0, 2, 1, 2><<<dim3(512 + 512), dim3(256), 36864, stream>>>(g4, g5, 512);
  }

  // ---- 5) merged output FFNs; A2 = f32 pools converted during staging ----
  {
    GemmP g{};
    g.A = Pbf; g.lda = Dd;
    g.A2f = pool_s; g.lda2 = HDd; g.kSplit = Dd;
    g.Bm = WfpT; g.ldb = CAT;
    g.C = d_out; g.ldc = Dd;
    g.bias = b_fp;
    g.A_b = Sbf; g.A2f_b = pool_p; g.Bm_b = WfsT;
    g.C_b = (float*)d_out + (size_t)Bb * L * Dd;
    g.bias_b = b_fs;
    g.M = Bb * L; g.N = Dd; g.K = CAT; g.Hh = 1; g.zSplit = 1;
    gemm_k<0, 3><<<dim3(64, 4, 2), dim3(256), 32768, stream>>>(g);
  }
}

// Round 3
// 316.733 us; speedup vs baseline: 1.4314x; 1.4314x over previous
//
#include <hip/hip_runtime.h>
#include <hip/hip_bf16.h>

typedef short short8 __attribute__((ext_vector_type(8)));
typedef float f32x16 __attribute__((ext_vector_type(16)));
typedef float f32x4 __attribute__((ext_vector_type(4)));

#define BM 128
#define BN 128

typedef const __attribute__((address_space(1))) void gas_t;
typedef __attribute__((address_space(3))) void las_t;

__device__ __forceinline__ unsigned short f2bf(float f) {
  unsigned int u = __float_as_uint(f);
  u += 0x7FFFu + ((u >> 16) & 1u);   // round-to-nearest-even
  return (unsigned short)(u >> 16);
}

// tanh via single v_exp_f32 + v_rcp_f32: tanh(x) = 1 - 2/(e^2x + 1).
__device__ __forceinline__ float fast_tanh(float x) {
  x = fminf(fmaxf(x, -10.f), 10.f);
  float t = __builtin_amdgcn_exp2f(x * 2.8853900817779268f);  // 2*log2(e)
  return 1.f - 2.f * __builtin_amdgcn_rcpf(t + 1.f);
}

struct GemmP {
  const unsigned short* A;
  const unsigned short* Bm;
  void* C;
  const float* A2f;            // f32 second A source for k >= kSplit (converted during staging)
  // alt pointer set for merged launches: used when z >= zSplit
  const unsigned short* A_b;
  const unsigned short* Bm_b;
  void* C_b;
  const float* A2f_b;
  const float* mask_p;
  const float* mask_s;
  const float* bias;
  const float* bias_b;
  long long sAb, sAh, sBb, sBh, sCb, sCh;
  int lda, lda2, ldb, ldc, M, N, K, Hh, kSplit, zSplit, nbx, nby;
};

// ---------------------------------------------------------------------------
// Legacy 128x128 / 256-thread kernel (kept for steps 4 and 5).
// TA: 0 = A is M x K row-major (lds-DMA staging, pitch 32); 1 = A stored K x M.
// EPI: 0 bf16 store; 1 tanh*mask bf16; 2 relu+atomicMax f32 pool; 3 +bias,relu f32.
template <int TA, int EPI>
__device__ __forceinline__ void gemm_body(const GemmP& p, int bx, int by, int bz, char* smem_) {
  constexpr int PA = (TA == 0) ? 32 : 40;
  constexpr int HSA = (TA == 0) ? 4096 : 5120;  // shorts per A half-tile
  unsigned short* As = (unsigned short*)smem_;
  unsigned short* Bs = (unsigned short*)(smem_ + 2 * HSA * 2);

  int z = bz;
  const unsigned short* Abase = p.A;
  const unsigned short* Bbase = p.Bm;
  void* Cvp = p.C;
  const float* A2f = p.A2f;
  const float* bias = p.bias;
  if (p.zSplit && z >= p.zSplit) {
    z -= p.zSplit;
    Abase = p.A_b; Bbase = p.Bm_b; Cvp = p.C_b; A2f = p.A2f_b; bias = p.bias_b;
  }
  const int zb = z / p.Hh, zh = z % p.Hh;
  const unsigned short* A = Abase + (size_t)zb * p.sAb + (size_t)zh * p.sAh;
  const unsigned short* B = Bbase + (size_t)zb * p.sBb + (size_t)zh * p.sBh;
  const int m0 = bx * BM, n0 = by * BN;
  const int tid = threadIdx.x;
  const int wid = tid >> 6, lane = tid & 63;
  const int wm = (wid >> 1) * 64, wn = (wid & 1) * 64;
  const int lrow = lane & 31;          // row within 32x32 frag
  const int lk8 = (lane >> 5) * 8;     // k-offset within 16-k chunk

  f32x16 acc[2][2] = {};

  const int dm = tid >> 2, dkg = tid & 3;

  auto mfma_block = [&]() {
#pragma unroll
    for (int h = 0; h < 2; ++h)
#pragma unroll
      for (int kc = 0; kc < 2; ++kc) {
        short8 af[2], bfv[2];
#pragma unroll
        for (int mt = 0; mt < 2; ++mt)
          af[mt] = *(const short8*)&As[h * HSA + (wm + mt * 32 + lrow) * PA + kc * 16 + lk8];
#pragma unroll
        for (int nt = 0; nt < 2; ++nt)
          bfv[nt] = *(const short8*)&Bs[h * 4096 + (wn + nt * 32 + lrow) * 32 + kc * 16 + lk8];
#pragma unroll
        for (int mt = 0; mt < 2; ++mt)
#pragma unroll
          for (int nt = 0; nt < 2; ++nt)
            acc[mt][nt] = __builtin_amdgcn_mfma_f32_32x32x16_bf16(af[mt], bfv[nt], acc[mt][nt], 0, 0, 0);
      }
  };
  auto stage_b = [&](int k0) {
#pragma unroll
    for (int h = 0; h < 2; ++h)
#pragma unroll
      for (int q = 0; q < 2; ++q) {
        const unsigned short* src = B + (size_t)(n0 + q * 64 + dm) * p.ldb + (k0 + h * 32 + dkg * 8);
        __builtin_amdgcn_global_load_lds((gas_t*)src,
                                         (las_t*)&Bs[h * 4096 + q * 2048 + wid * 512],
                                         16, 0, 0);
      }
  };

  const int nIter = p.K >> 6;
  const int nIter1 = p.kSplit ? (p.kSplit >> 6) : nIter;

  for (int it = 0; it < nIter1; ++it) {
    const int k0 = it << 6;
    if (TA == 0) {
#pragma unroll
      for (int h = 0; h < 2; ++h)
#pragma unroll
        for (int q = 0; q < 2; ++q) {
          const unsigned short* src = A + (size_t)(m0 + q * 64 + dm) * p.lda + (k0 + h * 32 + dkg * 8);
          __builtin_amdgcn_global_load_lds((gas_t*)src,
                                           (las_t*)&As[h * HSA + q * 2048 + wid * 512],
                                           16, 0, 0);
        }
    } else {
      const int kk = tid & 31, mg = (tid >> 5) << 4;
#pragma unroll
      for (int h = 0; h < 2; ++h) {
        const unsigned short* src = A + (size_t)(k0 + h * 32 + kk) * p.lda + (m0 + mg);
        uint4 v0 = *(const uint4*)src;
        uint4 v1 = *(const uint4*)(src + 8);
        unsigned short tmp[16];
        *(uint4*)&tmp[0] = v0;
        *(uint4*)&tmp[8] = v1;
#pragma unroll
        for (int j = 0; j < 16; ++j) As[h * HSA + (mg + j) * PA + kk] = tmp[j];
      }
    }
    stage_b(k0);
    __syncthreads();
    mfma_block();
    __syncthreads();
  }

  // phase 2 (TA=0 only in practice): A from f32 source with in-register convert
  if (TA == 0 && p.kSplit) {
    for (int it = nIter1; it < nIter; ++it) {
      const int k0 = it << 6;
#pragma unroll
      for (int h = 0; h < 2; ++h) {
        const int ko = k0 + h * 32 - p.kSplit;
#pragma unroll
        for (int q = 0; q < 2; ++q) {
          const float* src = A2f + (size_t)(m0 + q * 64 + dm) * p.lda2 + (ko + dkg * 8);
          float4 v0 = *(const float4*)src;
          float4 v1 = *(const float4*)(src + 4);
          __attribute__((aligned(16))) unsigned short t[8];
          t[0] = f2bf(v0.x); t[1] = f2bf(v0.y); t[2] = f2bf(v0.z); t[3] = f2bf(v0.w);
          t[4] = f2bf(v1.x); t[5] = f2bf(v1.y); t[6] = f2bf(v1.z); t[7] = f2bf(v1.w);
          *(uint4*)&As[h * HSA + (q * 64 + dm) * 32 + dkg * 8] = *(const uint4*)t;
        }
      }
      stage_b(k0);
      __syncthreads();
      mfma_block();
      __syncthreads();
    }
  }

  unsigned short* Cu = (unsigned short*)Cvp + (size_t)zb * p.sCb + (size_t)zh * p.sCh;
  float* Cf = (float*)Cvp + (size_t)zb * p.sCb + (size_t)zh * p.sCh;

  const int rbase = 4 * (lane >> 5);

  float mp[2][16], ms[2];
  if constexpr (EPI == 1) {
#pragma unroll
    for (int mt = 0; mt < 2; ++mt)
#pragma unroll
      for (int reg = 0; reg < 16; ++reg) {
        const int rl = (reg & 3) + 8 * (reg >> 2) + rbase;
        mp[mt][reg] = p.mask_p[(size_t)zb * p.M + (m0 + wm + mt * 32 + rl)];
      }
#pragma unroll
    for (int nt = 0; nt < 2; ++nt)
      ms[nt] = p.mask_s[(size_t)zb * p.N + (n0 + wn + nt * 32 + lrow)];
  }
  if constexpr (EPI == 3) {
#pragma unroll
    for (int nt = 0; nt < 2; ++nt)
      ms[nt] = bias[n0 + wn + nt * 32 + lrow];
  }

#pragma unroll
  for (int mt = 0; mt < 2; ++mt) {
#pragma unroll
    for (int nt = 0; nt < 2; ++nt) {
      f32x16 a = acc[mt][nt];
#pragma unroll
      for (int reg = 0; reg < 16; ++reg) {
        const int rl = (reg & 3) + 8 * (reg >> 2) + rbase;
        const int grow = m0 + wm + mt * 32 + rl;
        const int gcol = n0 + wn + nt * 32 + lrow;
        const size_t idx = (size_t)grow * p.ldc + gcol;
        const float v = a[reg];
        if constexpr (EPI == 0) {
          Cu[idx] = f2bf(v);
        } else if constexpr (EPI == 1) {
          Cu[idx] = f2bf(fast_tanh(v) * (mp[mt][reg] * ms[nt]));
        } else if constexpr (EPI == 2) {
          atomicMax((int*)Cf + idx, __float_as_int(fmaxf(v, 0.f)));
        } else {
          Cf[idx] = fmaxf(v + ms[nt], 0.f);
        }
      }
    }
  }
}

template <int TA, int EPI>
__global__ __launch_bounds__(256) void gemm_k(GemmP p) {
  extern __shared__ char smem[];
  gemm_body<TA, EPI>(p, blockIdx.x, blockIdx.y, blockIdx.z, smem);
}

template <int TA1, int EPI1, int TA2, int EPI2>
__global__ __launch_bounds__(256) void gemm_pair_k(GemmP a, GemmP b, int nA) {
  extern __shared__ char smem[];
  int bid = blockIdx.x;
  if (bid < nA) {
    const int per = a.nbx * a.nby;
    const int z = bid / per, r = bid % per;
    gemm_body<TA1, EPI1>(a, r % a.nbx, r / a.nbx, z, smem);
  } else {
    bid -= nA;
    const int per = b.nbx * b.nby;
    const int z = bid / per, r = bid % per;
    gemm_body<TA2, EPI2>(b, r % b.nbx, r / b.nbx, z, smem);
  }
}

// ---------------------------------------------------------------------------
// gemm10: 256x256 lds-DMA deep pipeline (steps 2 and 3) — m201-faithful geometry.
// 512 threads = 8 waves as 2(M) x 4(N); wave tile 128x64 = 8x4 frags of 16x16x32.
// Rationale (rounds 0-2 post-mortem): at 256x128 the LDS read port (~1536 cyc
// per K-tile) exceeds the MFMA pipe (1242 cyc) -> LDS-read-bound at 626 TF no
// matter the sync structure. 256x256 doubles MFMA per LDS byte: reads 192 KB
// (2260 cyc) vs MFMA 2483 cyc -> MFMA-bound.
// BK=64. LDS: 2 slots x 64 KiB (A 256x64 + B 256x64) = 128 KiB. Staging via
// global_load_lds width-16, LINEAR dest + inverse-swizzled GLOBAL source; reads
// XOR-swizzled byte ^= (row&7)<<4 (round-1-verified, 0 bank conflicts).
// Distance-1 prefetch into the other slot; ONE vmcnt(0)+barrier per K-tile
// (the waited loads were issued ~2000 cyc earlier -> no drain stall).
// __launch_bounds__(512,1): register cap >= 256 under either HIP/CUDA
// semantics (round-2's (512,2) capped at 128 and spilled acc -> 270 MB scratch).
// EPI: 0 = bf16 store; 1 = tanh*mask bf16.
#define VMW0() asm volatile("s_waitcnt vmcnt(0)" ::: "memory")

template <int EPI>
__device__ __forceinline__ void gemm10_body(const GemmP& p, int bx, int by, int bz, char* smem_) {
  int z = bz;
  const unsigned short* Abase = p.A;
  const unsigned short* Bbase = p.Bm;
  void* Cvp = p.C;
  if (p.zSplit && z >= p.zSplit) {
    z -= p.zSplit;
    Abase = p.A_b; Bbase = p.Bm_b; Cvp = p.C_b;
  }
  const int zb = z / p.Hh, zh = z % p.Hh;
  const unsigned short* A = Abase + (size_t)zb * p.sAb + (size_t)zh * p.sAh;
  const unsigned short* B = Bbase + (size_t)zb * p.sBb + (size_t)zh * p.sBh;
  const int m0 = bx * 256, n0 = by * 256;
  const int tid = threadIdx.x;
  const int wid = tid >> 6, lane = tid & 63;
  const int wm = wid >> 2, wn = wid & 3;        // 2 x 4 wave grid
  const int lrow = lane & 15, lhi = lane >> 4;  // MFMA 16x16x32 lane decomposition

  // staging source coords: LDS linear dest byte (region: s*8192 + tid*16) ->
  // row = s*64 + tid/8, col bytes = (tid&7)*16; source col = dest col ^ ((row&7)<<4)
  const int rr = tid >> 3;                              // 0..63
  const int cs = ((tid & 7) * 8) ^ ((rr & 7) << 3);     // source col, shorts

  // read-side swizzled lane offsets (bytes). row&7 == lrow&7 (frag rows are 16-aligned)
  const int colx = (lhi * 16) ^ ((lrow & 7) << 4);
  const int offA = (wm * 128 + lrow) * 128 + colx;            // A region, ks=0
  const int offB = 32768 + (wn * 64 + lrow) * 128 + colx;     // B region, ks=0

  f32x4 acc[8][4] = {};

  auto stageA = [&](int t, int slot) {
    const int k0 = t << 6;
    const unsigned short* s0 = A + (size_t)(m0 + rr) * p.lda + k0 + cs;
#pragma unroll
    for (int s = 0; s < 4; ++s)
      __builtin_amdgcn_global_load_lds((gas_t*)(s0 + (size_t)(s * 64) * p.lda),
                                       (las_t*)(smem_ + slot * 65536 + s * 8192 + tid * 16),
                                       16, 0, 0);
  };
  auto stageB = [&](int t, int slot) {
    const int k0 = t << 6;
    const unsigned short* s0 = B + (size_t)(n0 + rr) * p.ldb + k0 + cs;
#pragma unroll
    for (int s = 0; s < 4; ++s)
      __builtin_amdgcn_global_load_lds((gas_t*)(s0 + (size_t)(s * 64) * p.ldb),
                                       (las_t*)(smem_ + slot * 65536 + 32768 + s * 8192 + tid * 16),
                                       16, 0, 0);
  };

  const int nt = p.K >> 6;   // K-tiles of 64

  // prologue: tile 0 -> slot 0
  stageA(0, 0); stageB(0, 0);
  VMW0();
  __builtin_amdgcn_s_barrier();
  __builtin_amdgcn_sched_barrier(0);

  for (int t = 0; t < nt; ++t) {
    const int slot = t & 1, other = slot ^ 1;
    const char* sb = smem_ + slot * 65536;
    short8 af[4], bv[4];

    // ---- phase 0 (ks0, m-half 0): reads + stage A(t+1) + 16 MFMA
#pragma unroll
    for (int fn = 0; fn < 4; ++fn) bv[fn] = *(const short8*)(sb + offB + fn * 2048);
#pragma unroll
    for (int fm = 0; fm < 4; ++fm) af[fm] = *(const short8*)(sb + offA + fm * 2048);
    if (t + 1 < nt) stageA(t + 1, other);
    __builtin_amdgcn_s_setprio(1);
#pragma unroll
    for (int fm = 0; fm < 4; ++fm)
#pragma unroll
      for (int fn = 0; fn < 4; ++fn)
        acc[fm][fn] = __builtin_amdgcn_mfma_f32_16x16x32_bf16(af[fm], bv[fn], acc[fm][fn], 0, 0, 0);
    __builtin_amdgcn_s_setprio(0);

    // ---- phase 1 (ks0, m-half 1): reads + stage B(t+1) + 16 MFMA (bv held)
#pragma unroll
    for (int fm = 0; fm < 4; ++fm) af[fm] = *(const short8*)(sb + offA + (4 + fm) * 2048);
    if (t + 1 < nt) stageB(t + 1, other);
    __builtin_amdgcn_s_setprio(1);
#pragma unroll
    for (int fm = 0; fm < 4; ++fm)
#pragma unroll
      for (int fn = 0; fn < 4; ++fn)
        acc[4 + fm][fn] = __builtin_amdgcn_mfma_f32_16x16x32_bf16(af[fm], bv[fn], acc[4 + fm][fn], 0, 0, 0);
    __builtin_amdgcn_s_setprio(0);

    // ---- phase 2 (ks1, m-half 0): ks=1 via ^64 on the swizzled byte col
#pragma unroll
    for (int fn = 0; fn < 4; ++fn) bv[fn] = *(const short8*)(sb + (offB ^ 64) + fn * 2048);
#pragma unroll
    for (int fm = 0; fm < 4; ++fm) af[fm] = *(const short8*)(sb + (offA ^ 64) + fm * 2048);
    __builtin_amdgcn_s_setprio(1);
#pragma unroll
    for (int fm = 0; fm < 4; ++fm)
#pragma unroll
      for (int fn = 0; fn < 4; ++fn)
        acc[fm][fn] = __builtin_amdgcn_mfma_f32_16x16x32_bf16(af[fm], bv[fn], acc[fm][fn], 0, 0, 0);
    __builtin_amdgcn_s_setprio(0);

    // ---- phase 3 (ks1, m-half 1)
#pragma unroll
    for (int fm = 0; fm < 4; ++fm) af[fm] = *(const short8*)(sb + (offA ^ 64) + (4 + fm) * 2048);
    __builtin_amdgcn_s_setprio(1);
#pragma unroll
    for (int fm = 0; fm < 4; ++fm)
#pragma unroll
      for (int fn = 0; fn < 4; ++fn)
        acc[4 + fm][fn] = __builtin_amdgcn_mfma_f32_16x16x32_bf16(af[fm], bv[fn], acc[4 + fm][fn], 0, 0, 0);
    __builtin_amdgcn_s_setprio(0);

    // ---- tile boundary: next tile's loads (issued ~2000 cyc ago) must land
    if (t + 1 < nt) {
      VMW0();
      __builtin_amdgcn_s_barrier();
      __builtin_amdgcn_sched_barrier(0);
    }
  }

  // ---- epilogue ----
  unsigned short* Cu = (unsigned short*)Cvp + (size_t)zb * p.sCb + (size_t)zh * p.sCh;

  float ms[4];
  if constexpr (EPI == 1) {
#pragma unroll
    for (int fn = 0; fn < 4; ++fn)
      ms[fn] = p.mask_s[(size_t)zb * p.N + (n0 + wn * 64 + fn * 16 + lrow)];
  }

#pragma unroll
  for (int fm = 0; fm < 8; ++fm)
#pragma unroll
    for (int fn = 0; fn < 4; ++fn) {
      f32x4 a = acc[fm][fn];
      const int gcol = n0 + wn * 64 + fn * 16 + lrow;
#pragma unroll
      for (int reg = 0; reg < 4; ++reg) {
        const int grow = m0 + wm * 128 + fm * 16 + lhi * 4 + reg;
        const size_t idx = (size_t)grow * p.ldc + gcol;
        if constexpr (EPI == 0) {
          Cu[idx] = f2bf(a[reg]);
        } else {
          const float mp = p.mask_p[(size_t)zb * p.M + grow];
          Cu[idx] = f2bf(fast_tanh(a[reg]) * (mp * ms[fn]));
        }
      }
    }
}

template <int EPI>
__global__ __launch_bounds__(512, 1) void gemm10_k(GemmP p) {
  extern __shared__ char smem[];
  gemm10_body<EPI>(p, blockIdx.x, blockIdx.y, blockIdx.z, smem);
}

template <int E1, int E2>
__global__ __launch_bounds__(512, 1) void gemm10_pair_k(GemmP a, GemmP b, int nA) {
  extern __shared__ char smem[];
  int bid = blockIdx.x;
  if (bid < nA) {
    const int per = a.nbx * a.nby;
    const int z = bid / per, r = bid % per;
    gemm10_body<E1>(a, r % a.nbx, r / a.nbx, z, smem);
  } else {
    bid -= nA;
    const int per = b.nbx * b.nby;
    const int z = bid / per, r = bid % per;
    gemm10_body<E2>(b, r % b.nbx, r / b.nbx, z, smem);
  }
}

// ---- fused preamble: input cvt, 4 weight transposes, pool zeroing ----
__device__ __forceinline__ void trans_body(const float* src, unsigned short* dst,
                                           int R, int C, int bx, int by, float (*tile)[33]) {
  const int r0 = by * 32, c0 = bx * 32;
  const int tx = threadIdx.x & 31, ty = threadIdx.x >> 5;  // 32 x 8
#pragma unroll
  for (int j = 0; j < 4; ++j)
    tile[ty + j * 8][tx] = src[(size_t)(r0 + ty + j * 8) * C + (c0 + tx)];
  __syncthreads();
#pragma unroll
  for (int j = 0; j < 4; ++j)
    dst[(size_t)(c0 + ty + j * 8) * R + (r0 + tx)] = f2bf(tile[tx][ty + j * 8]);
}

__global__ __launch_bounds__(256) void prep_k(const float* P, const float* S,
                                              unsigned short* Pbf, unsigned short* Sbf,
                                              const float* W_aff, unsigned short* WaT,
                                              const float* W_p, unsigned short* WpT,
                                              const float* W_s, unsigned short* WsT,
                                              const float* W_fp, unsigned short* WfpT,
                                              const float* W_fs, unsigned short* WfsT,
                                              float* poolz) {
  __shared__ float tile[32][33];
  const int bid = blockIdx.x;
  if (bid < 8192) {
    const int n4 = 1048576;  // 16*512*512/4
    int i = bid * 256 + threadIdx.x;
    const float4* s = (const float4*)P;
    ushort4* d = (ushort4*)Pbf;
    if (i >= n4) { i -= n4; s = (const float4*)S; d = (ushort4*)Sbf; }
    float4 v = s[i];
    ushort4 o;
    o.x = f2bf(v.x); o.y = f2bf(v.y); o.z = f2bf(v.z); o.w = f2bf(v.w);
    d[i] = o;
  } else if (bid < 10240) {
    const int l = bid - 8192;                      // 16x16 tiles x 8 heads
    const int z = l >> 8, r = l & 255;
    trans_body(W_aff + (size_t)z * 262144, WaT + (size_t)z * 262144, 512, 512,
               r & 15, r >> 4, tile);
  } else if (bid < 11264) {
    const int l = bid - 10240;                     // 32x16 tiles x 2
    const int z = l >> 9, r = l & 511;
    trans_body(z ? W_s : W_p, z ? WsT : WpT, 512, 1024, r & 31, r >> 5, tile);
  } else if (bid < 11904) {
    const int l = bid - 11264;                     // 16x20 tiles x 2
    const int z = l / 320, r = l % 320;
    trans_body(z ? W_fs : W_fp, z ? WfsT : WfpT, 640, 512, r & 15, r >> 4, tile);
  } else {
    const int i = (bid - 11904) * 256 + threadIdx.x;  // 524288 float4s = 8.4 MB
    ((float4*)poolz)[i] = float4{0.f, 0.f, 0.f, 0.f};
  }
}

extern "C" void kernel_launch(void* const* d_in, const int* in_sizes, int n_in,
                              void* d_out, int out_size, void* d_ws, size_t ws_size,
                              hipStream_t stream) {
  (void)in_sizes; (void)n_in; (void)out_size; (void)ws_size;
  const float* primary   = (const float*)d_in[0];
  const float* secondary = (const float*)d_in[1];
  const float* pmask     = (const float*)d_in[2];
  const float* smask     = (const float*)d_in[3];
  const float* W_aff     = (const float*)d_in[4];
  const float* W_p       = (const float*)d_in[5];
  const float* W_s       = (const float*)d_in[6];
  const float* W_fp      = (const float*)d_in[7];
  const float* b_fp      = (const float*)d_in[8];
  const float* W_fs      = (const float*)d_in[9];
  const float* b_fs      = (const float*)d_in[10];

  constexpr int Bb = 16, L = 512, Dd = 512, Hh = 8, HDd = 128, INNER = 1024, CAT = 640;
  constexpr int NT = Hh * Dd;                      // 4096
  constexpr long long LD = (long long)L * Dd;      // 262144
  constexpr long long LL = (long long)L * L;       // 262144

  // one-time: allow 128 KiB dynamic LDS on the gemm10 kernels
  static bool s_attr = [] {
    hipFuncSetAttribute(reinterpret_cast<const void*>(&gemm10_pair_k<0, 0>),
                        hipFuncAttributeMaxDynamicSharedMemorySize, 131072);
    hipFuncSetAttribute(reinterpret_cast<const void*>(&gemm10_k<1>),
                        hipFuncAttributeMaxDynamicSharedMemorySize, 131072);
    return true;
  }();
  (void)s_attr;

  char* base = (char*)d_ws;
  size_t off = 0;
  auto alloc = [&](size_t bytes) -> void* {
    void* r = base + off;
    off += (bytes + 255) & ~(size_t)255;
    return r;
  };

  unsigned short* Pbf   = (unsigned short*)alloc((size_t)Bb * L * Dd * 2);
  unsigned short* Sbf   = (unsigned short*)alloc((size_t)Bb * L * Dd * 2);
  unsigned short* WaT   = (unsigned short*)alloc((size_t)NT * Dd * 2);        // [h*512+f][e]
  unsigned short* WpT   = (unsigned short*)alloc((size_t)INNER * Dd * 2);     // [n][e]
  unsigned short* WsT   = (unsigned short*)alloc((size_t)INNER * Dd * 2);
  unsigned short* WfpT  = (unsigned short*)alloc((size_t)Dd * CAT * 2);       // [n][k]
  unsigned short* WfsT  = (unsigned short*)alloc((size_t)Dd * CAT * 2);
  unsigned short* psT   = (unsigned short*)alloc((size_t)Bb * INNER * L * 2); // [b][d][j]
  unsigned short* ppT   = (unsigned short*)alloc((size_t)Bb * INNER * L * 2); // [b][d][i]
  unsigned short* Tbuf  = (unsigned short*)alloc((size_t)Bb * L * NT * 2);    // [b*L+i][h*512+f]
  unsigned short* affb  = (unsigned short*)alloc((size_t)Bb * Hh * L * L * 2);
  float* pool_p = (float*)alloc((size_t)Bb * L * HDd * 4);                    // adjacent with pool_s
  float* pool_s = (float*)alloc((size_t)Bb * L * HDd * 4);

  // ---- 1) fused preamble ----
  prep_k<<<dim3(13952), dim3(256), 0, stream>>>(primary, secondary, Pbf, Sbf,
                                                W_aff, WaT, W_p, WpT, W_s, WsT,
                                                W_fp, WfpT, W_fs, WfsT, pool_p);

  // ---- 2) Tbuf = P @ Waff(stacked)  ||  psT/ppT = (S@W_s)^T / (P@W_p)^T ----
  // gemm10: 256x256 lds-DMA pipeline, 512 threads, 2-slot dbuf
  {
    GemmP a{};
    a.A = Pbf; a.lda = Dd;
    a.Bm = WaT; a.ldb = Dd;
    a.C = Tbuf; a.ldc = NT;
    a.M = Bb * L; a.N = NT; a.K = Dd; a.Hh = 1; a.nbx = 32; a.nby = 16;

    GemmP b{};
    b.A = WsT; b.lda = Dd; b.sAb = 0;
    b.Bm = Sbf; b.ldb = Dd; b.sBb = LD;
    b.C = psT; b.ldc = L; b.sCb = (long long)INNER * L;
    b.A_b = WpT; b.Bm_b = Pbf; b.C_b = ppT;
    b.M = INNER; b.N = L; b.K = Dd; b.Hh = 1; b.zSplit = Bb; b.nbx = 4; b.nby = 2;

    gemm10_pair_k<0, 0><<<dim3(512 + 256), dim3(512), 131072, stream>>>(a, b, 512);
  }

  // ---- 3) aff[b,h] = tanh(T[b,h] @ S_b^T) * mask ----
  {
    GemmP g{};
    g.A = Tbuf; g.lda = NT; g.sAb = (long long)L * NT; g.sAh = Dd;
    g.Bm = Sbf; g.ldb = Dd; g.sBb = LD; g.sBh = 0;
    g.C = affb; g.ldc = L; g.sCb = (long long)Hh * LL; g.sCh = LL;
    g.mask_p = pmask; g.mask_s = smask;
    g.M = L; g.N = L; g.K = Dd; g.Hh = Hh;
    gemm10_k<1><<<dim3(2, 2, Bb * Hh), dim3(512), 131072, stream>>>(g);
  }

  // ---- 4) pool_s (fast A)  ||  pool_p (A = affb as K x M) ----
  {
    GemmP g4{};
    g4.A = affb; g4.lda = L; g4.sAb = (long long)Hh * LL; g4.sAh = LL;
    g4.Bm = psT; g4.ldb = L; g4.sBb = (long long)INNER * L; g4.sBh = (long long)HDd * L;
    g4.C = pool_s; g4.ldc = HDd; g4.sCb = (long long)L * HDd; g4.sCh = 0;
    g4.M = L; g4.N = HDd; g4.K = L; g4.Hh = Hh; g4.nbx = 4; g4.nby = 1;

    GemmP g5 = g4;
    g5.Bm = ppT;
    g5.C = pool_p;

    gemm_pair_k<0, 2, 1, 2><<<dim3(512 + 512), dim3(256), 36864, stream>>>(g4, g5, 512);
  }

  // ---- 5) merged output FFNs; A2 = f32 pools converted during staging ----
  {
    GemmP g{};
    g.A = Pbf; g.lda = Dd;
    g.A2f = pool_s; g.lda2 = HDd; g.kSplit = Dd;
    g.Bm = WfpT; g.ldb = CAT;
    g.C = d_out; g.ldc = Dd;
    g.bias = b_fp;
    g.A_b = Sbf; g.A2f_b = pool_p; g.Bm_b = WfsT;
    g.C_b = (float*)d_out + (size_t)Bb * L * Dd;
    g.bias_b = b_fs;
    g.M = Bb * L; g.N = Dd; g.K = CAT; g.Hh = 1; g.zSplit = 1;
    gemm_k<0, 3><<<dim3(64, 4, 2), dim3(256), 32768, stream>>>(g);
  }
}